// Round 8
// baseline (348.654 us; speedup 1.0000x reference)
//
#include <hip/hip_runtime.h>
#include <hip/hip_bf16.h>

// Net_40089224741482 round 8: m97-replica GEMM (16x16x32 f16, 4x4 accumulators).
//  32x32x16 with 2x2 accs starved the MFMA pipe (4 dependency chains, MfmaUtil 20%);
//  m97's measured-874TF structure uses 16x16x32 with 16 independent accs. Rebuilt
//  dgemm accordingly: BK=64 single-buffer, fragment-order LDS, global_load_lds w16.
//  Fragment layouts (HW-verified per guide m89/m91/m120):
//    A/B operand: row(col)=lane&15, k=(lane>>4)*8+j   (one dwordx4 per frag)
//    C/D:         col=lane&15, row=(lane>>4)*4+reg

typedef _Float16 half8 __attribute__((ext_vector_type(8)));
typedef _Float16 half4v __attribute__((ext_vector_type(4)));
typedef float floatx4 __attribute__((ext_vector_type(4)));

namespace {
constexpr int kB = 4096, kS = 128, kA = 32, kH = 1024, kN = 256;
constexpr size_t al(size_t x) { return (x + 255) & ~size_t(255); }
// layout: FLAG | S16 | WEXPT | BUF2 | VAL | [weights+BUF1 region, aliased by Z]
constexpr size_t OFF_FLAG  = 0;
constexpr size_t OFF_S16   = 256;
constexpr size_t OFF_WEXPT = OFF_S16   + al((size_t)kB * kS * 2);
constexpr size_t OFF_BUF2  = OFF_WEXPT + al((size_t)kN * kA * kH * 2);
constexpr size_t OFF_VAL   = OFF_BUF2  + al((size_t)kB * kH * 2);
constexpr size_t OFF_WV1T  = OFF_VAL   + al((size_t)kB * kN * 4);
constexpr size_t OFF_WV2T  = OFF_WV1T  + al((size_t)kS * kH * 2);
constexpr size_t OFF_WV3T  = OFF_WV2T  + al((size_t)kH * kH * 2);
constexpr size_t OFF_WV4T  = OFF_WV3T  + al((size_t)kH * kH * 2);
constexpr size_t OFF_WL1T  = OFF_WV4T  + al((size_t)kH * kN * 2);
constexpr size_t OFF_BUF1  = OFF_WL1T  + al((size_t)kS * kH * 2);
constexpr size_t OFF_Z     = OFF_WV1T;  // aliases weights+BUF1 (all dead before Z written)
} // namespace

__device__ __forceinline__ float ldraw(const void* p, size_t i, int bf) {
    if (bf) return __uint_as_float(((unsigned)((const unsigned short*)p)[i]) << 16);
    return ((const float*)p)[i];
}

__device__ __forceinline__ float4 ldraw4(const void* p, size_t i, int bf) {
    if (bf) {
        ushort4 u = *(const ushort4*)((const unsigned short*)p + i);
        return make_float4(__uint_as_float((unsigned)u.x << 16),
                           __uint_as_float((unsigned)u.y << 16),
                           __uint_as_float((unsigned)u.z << 16),
                           __uint_as_float((unsigned)u.w << 16));
    }
    return *(const float4*)((const float*)p + i);
}

__device__ __forceinline__ void gl_lds16(const _Float16* g, _Float16* l) {
    __builtin_amdgcn_global_load_lds(
        (const __attribute__((address_space(1))) unsigned int*)g,
        (__attribute__((address_space(3))) unsigned int*)l, 16, 0, 0);
}

__device__ __forceinline__ float fast_tanh(float x) {
    x = fminf(9.f, fmaxf(-9.f, x));
    float e = __expf(2.f * x);
    return (e - 1.f) * __builtin_amdgcn_rcpf(e + 1.f);
}

// --- dtype detection, parallel: low 16 bits of fp32 N(0,1) are uniform mantissa
// bits; for packed bf16 they are a bf16 value whose exponent sits near 127.
__global__ void detect_kernel(const unsigned int* __restrict__ s_raw, int* __restrict__ flag) {
    __shared__ int cnt;
    if (threadIdx.x == 0) cnt = 0;
    __syncthreads();
    const unsigned e = (s_raw[threadIdx.x] >> 7) & 0xFFu;
    int c = (e >= 118u && e <= 135u) ? 1 : 0;
    for (int off = 32; off > 0; off >>= 1) c += __shfl_down(c, off);
    if ((threadIdx.x & 63) == 0) atomicAdd(&cnt, c);
    __syncthreads();
    if (threadIdx.x == 0) *flag = (cnt > 128) ? 1 : 0;
}

__global__ void convert_to_f16(const void* __restrict__ src, _Float16* __restrict__ dst,
                               int n, const int* __restrict__ flag) {
    const int bf = *flag;
    int i = blockIdx.x * blockDim.x + threadIdx.x;
    const int stride = gridDim.x * blockDim.x;
    for (; i < n; i += stride) dst[i] = (_Float16)ldraw(src, i, bf);
}

// --- ALL weight transposes in one dispatch: src [Z][K][N] -> dst [Z][N][K] f16
struct TDesc { const void* src; _Float16* dst; int K; int N; int tiles; };
struct TPack { TDesc d[6]; };

__global__ void transpose_all(TPack p, const int* __restrict__ flag) {
    __shared__ float tile[32][33];
    const int bf = *flag;
    int bid = blockIdx.x;
    int i = 0;
    while (bid >= p.d[i].tiles) { bid -= p.d[i].tiles; ++i; }
    const int K = p.d[i].K, N = p.d[i].N;
    const int tpz = (N >> 5) * (K >> 5);
    const int z = bid / tpz, r = bid - z * tpz;
    const int n0 = (r % (N >> 5)) * 32, k0 = (r / (N >> 5)) * 32;
    const size_t zo = (size_t)z * K * N;
    const void* src = p.d[i].src;
    _Float16* dst = p.d[i].dst;
    const int tx = threadIdx.x, ty = threadIdx.y;  // tx 0..7, ty 0..31
    float4 v = ldraw4(src, zo + (size_t)(k0 + ty) * N + n0 + tx * 4, bf);
    tile[ty][tx * 4 + 0] = v.x;
    tile[ty][tx * 4 + 1] = v.y;
    tile[ty][tx * 4 + 2] = v.z;
    tile[ty][tx * 4 + 3] = v.w;
    __syncthreads();
    half4v o;
#pragma unroll
    for (int j = 0; j < 4; ++j) o[j] = (_Float16)tile[tx * 4 + j][ty];
    *(half4v*)(dst + zo + (size_t)(n0 + ty) * K + k0 + tx * 4) = o;
}

// --- m97-style MFMA GEMM: C[M,N] = act(A[M,K] @ Bt[N,K]^T + bias)
// 256 thr = 4 waves (2x2); wave tile (TM/2)x(TN/2) as MIxNI 16x16x32 MFMAs
// (MI*NI independent accumulators -> MFMA-pipe ILP). BK=64 single-buffered.
// LDS fragment order: chunk c = (kb*(T/16)+rb)*64+lane holds
//   X[rb*16+(lane&15)][kb*32+(lane>>4)*8 ..+7]
// so global_load_lds (base+lane*16) and ds_read_b128 are both dense/conflict-free.
template <int TM, int TN, int DO_RELU, int OUT_F16>
__launch_bounds__(256)
__global__ void dgemm(const _Float16* __restrict__ A, const _Float16* __restrict__ Bt,
                      const void* __restrict__ bias_raw, void* __restrict__ Cout,
                      const int* __restrict__ flagp, int N, int K) {
    constexpr int BK = 64;
    constexpr int MI = TM / 32, NI = TN / 32;     // 16-row blocks per wave (waves 2x2)
    constexpr int ACH = TM * BK / 8;              // 16B chunks per stage
    constexpr int BCH = TN * BK / 8;
    constexpr int AT = ACH / 256, BT = BCH / 256; // chunks per thread
    __shared__ _Float16 As[ACH * 8];
    __shared__ _Float16 Bs[BCH * 8];

    const int tid = threadIdx.x;
    const int lane = tid & 63;
    const int wr = (tid >> 6) >> 1, wc = (tid >> 6) & 1;
    const int m0 = blockIdx.x * TM, n0 = blockIdx.y * TN;
    const int lrow = lane & 15, lkc = lane >> 4;  // fragment row/col, k-chunk

    // staging decode: chunk c = t*256+tid; kb = c/(T*4); rem = c%(T*4) (rem&63==lane)
    const _Float16* gAsrc[AT];
    _Float16* lAdst[AT];
#pragma unroll
    for (int t = 0; t < AT; ++t) {
        const int c = t * 256 + tid;
        const int kb = c / (TM * 4), rem = c % (TM * 4);
        const int row = (rem >> 6) * 16 + lrow;
        const int kcol = kb * 32 + lkc * 8;
        gAsrc[t] = A + (size_t)(m0 + row) * K + kcol;
        lAdst[t] = As + (size_t)c * 8;
    }
    const _Float16* gBsrc[BT];
    _Float16* lBdst[BT];
#pragma unroll
    for (int t = 0; t < BT; ++t) {
        const int c = t * 256 + tid;
        const int kb = c / (TN * 4), rem = c % (TN * 4);
        const int row = (rem >> 6) * 16 + lrow;
        const int kcol = kb * 32 + lkc * 8;
        gBsrc[t] = Bt + (size_t)(n0 + row) * K + kcol;
        lBdst[t] = Bs + (size_t)c * 8;
    }

    floatx4 acc[MI][NI];
#pragma unroll
    for (int mi = 0; mi < MI; ++mi)
#pragma unroll
        for (int ni = 0; ni < NI; ++ni)
#pragma unroll
            for (int i = 0; i < 4; ++i) acc[mi][ni][i] = 0.f;

    for (int k0 = 0; k0 < K; k0 += BK) {
#pragma unroll
        for (int t = 0; t < AT; ++t) gl_lds16(gAsrc[t] + k0, lAdst[t]);
#pragma unroll
        for (int t = 0; t < BT; ++t) gl_lds16(gBsrc[t] + k0, lBdst[t]);
        __syncthreads();
#pragma unroll
        for (int kb = 0; kb < 2; ++kb) {
            half8 af[MI], bfr[NI];
#pragma unroll
            for (int mi = 0; mi < MI; ++mi)
                af[mi] = *(const half8*)(As + ((size_t)((kb * (TM / 16) + wr * MI + mi) * 64 + lane)) * 8);
#pragma unroll
            for (int ni = 0; ni < NI; ++ni)
                bfr[ni] = *(const half8*)(Bs + ((size_t)((kb * (TN / 16) + wc * NI + ni) * 64 + lane)) * 8);
#pragma unroll
            for (int mi = 0; mi < MI; ++mi)
#pragma unroll
                for (int ni = 0; ni < NI; ++ni)
                    acc[mi][ni] = __builtin_amdgcn_mfma_f32_16x16x32_f16(af[mi], bfr[ni], acc[mi][ni], 0, 0, 0);
        }
        __syncthreads();
    }

    const int bf_ = *flagp;
#pragma unroll
    for (int mi = 0; mi < MI; ++mi)
#pragma unroll
        for (int ni = 0; ni < NI; ++ni) {
            const int Rb = m0 + (wr * MI + mi) * 16 + lkc * 4;  // + reg
            const int Cb = n0 + (wc * NI + ni) * 16 + lrow;     // col
            const float bv = ldraw(bias_raw, Cb, bf_);
#pragma unroll
            for (int r = 0; r < 4; ++r) {
                float x = acc[mi][ni][r] + bv;
                if (DO_RELU) x = fmaxf(x, 0.f);
                if (OUT_F16) ((_Float16*)Cout)[(size_t)(Rb + r) * N + Cb] = (_Float16)x;
                else ((float*)Cout)[(size_t)(Rb + r) * N + Cb] = x;
            }
        }
}

// --- fused: tanh(z) -> ||c-a|| -> softmax(-dist) . values, one block per b
// NOTE: z already includes the bexp bias (added in the expert GEMM epilogue).
__launch_bounds__(256)
__global__ void final_fused(const _Float16* __restrict__ z, const void* __restrict__ a_raw,
                            const float* __restrict__ values, const int* __restrict__ flag,
                            void* __restrict__ out) {
    const int b = blockIdx.x;
    const int n = threadIdx.x;
    const int bf = *flag;
    __shared__ float as_[32];
    if (n < 32) as_[n] = ldraw(a_raw, (size_t)b * kA + n, bf);
    __syncthreads();

    const _Float16* zp = z + (size_t)b * (kN * kA) + n * kA;
    float zl[32];
#pragma unroll
    for (int t = 0; t < 4; ++t) {
        half8 h = *(const half8*)(zp + t * 8);
#pragma unroll
        for (int j = 0; j < 8; ++j) zl[t * 8 + j] = (float)h[j];
    }
    float sum = 0.f;
#pragma unroll
    for (int a = 0; a < 32; ++a) {
        const float c = fast_tanh(zl[a]);  // MAX_A=1; bexp already in z
        const float d = c - as_[a];
        sum = fmaf(d, d, sum);
    }
    const float dist = sqrtf(sum + 0.01f);
    const float v = values[(size_t)b * kN + n];

    const int wid = n >> 6, lane = n & 63;
    __shared__ float red[8];
    __shared__ float rw[4], rwv[4];
    float m = dist;
    for (int off = 32; off > 0; off >>= 1) m = fminf(m, __shfl_down(m, off));
    if (lane == 0) red[wid] = m;
    __syncthreads();
    if (n == 0) red[4] = fminf(fminf(red[0], red[1]), fminf(red[2], red[3]));
    __syncthreads();
    const float dmin = red[4];

    float wgt = expf(dmin - dist);
    float wv = wgt * v;
    for (int off = 32; off > 0; off >>= 1) {
        wgt += __shfl_down(wgt, off);
        wv += __shfl_down(wv, off);
    }
    if (lane == 0) { rw[wid] = wgt; rwv[wid] = wv; }
    __syncthreads();
    if (n == 0) {
        const float sw = rw[0] + rw[1] + rw[2] + rw[3];
        const float swv = rwv[0] + rwv[1] + rwv[2] + rwv[3];
        const float o = swv / sw;
        if (bf) ((__hip_bfloat16*)out)[b] = __float2bfloat16(o);
        else    ((float*)out)[b] = o;
    }
}

extern "C" void kernel_launch(void* const* d_in, const int* in_sizes, int n_in,
                              void* d_out, int out_size, void* d_ws, size_t ws_size,
                              hipStream_t stream) {
    (void)in_sizes; (void)n_in; (void)out_size; (void)ws_size;
    char* ws = (char*)d_ws;
    int* flag = (int*)(ws + OFF_FLAG);
    _Float16* s16   = (_Float16*)(ws + OFF_S16);
    _Float16* wv1t  = (_Float16*)(ws + OFF_WV1T);
    _Float16* wv2t  = (_Float16*)(ws + OFF_WV2T);
    _Float16* wv3t  = (_Float16*)(ws + OFF_WV3T);
    _Float16* wv4t  = (_Float16*)(ws + OFF_WV4T);
    _Float16* wl1t  = (_Float16*)(ws + OFF_WL1T);
    _Float16* wexpt = (_Float16*)(ws + OFF_WEXPT);
    _Float16* buf1  = (_Float16*)(ws + OFF_BUF1);
    _Float16* buf2  = (_Float16*)(ws + OFF_BUF2);
    float* values   = (float*)(ws + OFF_VAL);
    _Float16* z     = (_Float16*)(ws + OFF_Z);

    detect_kernel<<<1, 256, 0, stream>>>((const unsigned int*)d_in[0], flag);
    convert_to_f16<<<512, 256, 0, stream>>>(d_in[0], s16, kB * kS, flag);

    TPack tp;
    tp.d[0] = {d_in[2],  wv1t,  kS, kH, (kH / 32) * (kS / 32)};          // 128
    tp.d[1] = {d_in[4],  wv2t,  kH, kH, (kH / 32) * (kH / 32)};          // 1024
    tp.d[2] = {d_in[6],  wv3t,  kH, kH, (kH / 32) * (kH / 32)};          // 1024
    tp.d[3] = {d_in[8],  wv4t,  kH, kN, (kN / 32) * (kH / 32)};          // 256
    tp.d[4] = {d_in[10], wl1t,  kS, kH, (kH / 32) * (kS / 32)};          // 128
    tp.d[5] = {d_in[12], wexpt, kH, kA, kN * (kA / 32) * (kH / 32)};     // 8192
    int total_tiles = 0;
    for (int i = 0; i < 6; ++i) total_tiles += tp.d[i].tiles;            // 10752
    transpose_all<<<total_tiles, dim3(8, 32), 0, stream>>>(tp, flag);

    // value MLP
    dgemm<64, 64, 1, 1><<<dim3(kB / 64, kH / 64), 256, 0, stream>>>(s16,  wv1t, d_in[3], buf1, flag, kH, kS);
    dgemm<128, 64, 1, 1><<<dim3(kB / 128, kH / 64), 256, 0, stream>>>(buf1, wv2t, d_in[5], buf2, flag, kH, kH);
    dgemm<128, 64, 1, 1><<<dim3(kB / 128, kH / 64), 256, 0, stream>>>(buf2, wv3t, d_in[7], buf1, flag, kH, kH);
    dgemm<64, 64, 0, 0><<<dim3(kB / 64, kN / 64), 256, 0, stream>>>(buf1, wv4t, d_in[9], values, flag, kN, kH);
    // location hidden
    dgemm<64, 64, 1, 1><<<dim3(kB / 64, kH / 64), 256, 0, stream>>>(s16,  wl1t, d_in[11], buf2, flag, kH, kS);
    // expert heads: z[B, N*A] = buf2 @ wexpt^T + bexp (bias added HERE, once)
    dgemm<128, 128, 0, 1><<<dim3(kB / 128, (kN * kA) / 128), 256, 0, stream>>>(buf2, wexpt, d_in[13], z, flag, kN * kA, kH);
    // fused tanh + distance + softmax + value readout
    final_fused<<<kB, 256, 0, stream>>>(z, d_in[1], values, flag, d_out);
}

// Round 9
// 346.551 us; speedup vs baseline: 1.0061x; 1.0061x over previous
//
#include <hip/hip_runtime.h>
#include <hip/hip_bf16.h>

// Net_40089224741482 round 9: r7 structure + XCD-aware block swizzle.
//  Theory: expert GEMM is L3-BW-bound (1.07 GB staging demand served at 7.3 TB/s;
//  round-robin block->XCD dispatch defeats L2 reuse). Swizzle maps each XCD
//  (bid&7) to a compact tile region (n-band, 8x8 super-tile walk) so A/B re-reads
//  hit the XCD's own 4MB L2 (34.5 TB/s) instead of L3.

typedef _Float16 half8 __attribute__((ext_vector_type(8)));
typedef _Float16 half4v __attribute__((ext_vector_type(4)));
typedef float floatx16 __attribute__((ext_vector_type(16)));

namespace {
constexpr int kB = 4096, kS = 128, kA = 32, kH = 1024, kN = 256;
constexpr size_t al(size_t x) { return (x + 255) & ~size_t(255); }
// layout: FLAG | S16 | WEXPT | BUF2 | VAL | [weights+BUF1 region, aliased by Z]
constexpr size_t OFF_FLAG  = 0;
constexpr size_t OFF_S16   = 256;
constexpr size_t OFF_WEXPT = OFF_S16   + al((size_t)kB * kS * 2);
constexpr size_t OFF_BUF2  = OFF_WEXPT + al((size_t)kN * kA * kH * 2);
constexpr size_t OFF_VAL   = OFF_BUF2  + al((size_t)kB * kH * 2);
constexpr size_t OFF_WV1T  = OFF_VAL   + al((size_t)kB * kN * 4);
constexpr size_t OFF_WV2T  = OFF_WV1T  + al((size_t)kS * kH * 2);
constexpr size_t OFF_WV3T  = OFF_WV2T  + al((size_t)kH * kH * 2);
constexpr size_t OFF_WV4T  = OFF_WV3T  + al((size_t)kH * kH * 2);
constexpr size_t OFF_WL1T  = OFF_WV4T  + al((size_t)kH * kN * 2);
constexpr size_t OFF_BUF1  = OFF_WL1T  + al((size_t)kS * kH * 2);
constexpr size_t OFF_Z     = OFF_WV1T;  // aliases weights+BUF1 (all dead before Z written)
} // namespace

__device__ __forceinline__ float ldraw(const void* p, size_t i, int bf) {
    if (bf) return __uint_as_float(((unsigned)((const unsigned short*)p)[i]) << 16);
    return ((const float*)p)[i];
}

__device__ __forceinline__ float4 ldraw4(const void* p, size_t i, int bf) {
    if (bf) {
        ushort4 u = *(const ushort4*)((const unsigned short*)p + i);
        return make_float4(__uint_as_float((unsigned)u.x << 16),
                           __uint_as_float((unsigned)u.y << 16),
                           __uint_as_float((unsigned)u.z << 16),
                           __uint_as_float((unsigned)u.w << 16));
    }
    return *(const float4*)((const float*)p + i);
}

__device__ __forceinline__ void gl_lds16(const _Float16* g, _Float16* l) {
    __builtin_amdgcn_global_load_lds(
        (const __attribute__((address_space(1))) unsigned int*)g,
        (__attribute__((address_space(3))) unsigned int*)l, 16, 0, 0);
}

__device__ __forceinline__ float fast_tanh(float x) {
    x = fminf(9.f, fmaxf(-9.f, x));
    float e = __expf(2.f * x);
    return (e - 1.f) * __builtin_amdgcn_rcpf(e + 1.f);
}

// --- dtype detection, parallel: low 16 bits of fp32 N(0,1) are uniform mantissa
// bits; for packed bf16 they are a bf16 value whose exponent sits near 127.
__global__ void detect_kernel(const unsigned int* __restrict__ s_raw, int* __restrict__ flag) {
    __shared__ int cnt;
    if (threadIdx.x == 0) cnt = 0;
    __syncthreads();
    const unsigned e = (s_raw[threadIdx.x] >> 7) & 0xFFu;
    int c = (e >= 118u && e <= 135u) ? 1 : 0;
    for (int off = 32; off > 0; off >>= 1) c += __shfl_down(c, off);
    if ((threadIdx.x & 63) == 0) atomicAdd(&cnt, c);
    __syncthreads();
    if (threadIdx.x == 0) *flag = (cnt > 128) ? 1 : 0;
}

__global__ void convert_to_f16(const void* __restrict__ src, _Float16* __restrict__ dst,
                               int n, const int* __restrict__ flag) {
    const int bf = *flag;
    int i = blockIdx.x * blockDim.x + threadIdx.x;
    const int stride = gridDim.x * blockDim.x;
    for (; i < n; i += stride) dst[i] = (_Float16)ldraw(src, i, bf);
}

// --- ALL weight transposes in one dispatch: src [Z][K][N] -> dst [Z][N][K] f16
struct TDesc { const void* src; _Float16* dst; int K; int N; int tiles; };
struct TPack { TDesc d[6]; };

__global__ void transpose_all(TPack p, const int* __restrict__ flag) {
    __shared__ float tile[32][33];
    const int bf = *flag;
    int bid = blockIdx.x;
    int i = 0;
    while (bid >= p.d[i].tiles) { bid -= p.d[i].tiles; ++i; }
    const int K = p.d[i].K, N = p.d[i].N;
    const int tpz = (N >> 5) * (K >> 5);
    const int z = bid / tpz, r = bid - z * tpz;
    const int n0 = (r % (N >> 5)) * 32, k0 = (r / (N >> 5)) * 32;
    const size_t zo = (size_t)z * K * N;
    const void* src = p.d[i].src;
    _Float16* dst = p.d[i].dst;
    const int tx = threadIdx.x, ty = threadIdx.y;  // tx 0..7, ty 0..31
    float4 v = ldraw4(src, zo + (size_t)(k0 + ty) * N + n0 + tx * 4, bf);
    tile[ty][tx * 4 + 0] = v.x;
    tile[ty][tx * 4 + 1] = v.y;
    tile[ty][tx * 4 + 2] = v.z;
    tile[ty][tx * 4 + 3] = v.w;
    __syncthreads();
    half4v o;
#pragma unroll
    for (int j = 0; j < 4; ++j) o[j] = (_Float16)tile[tx * 4 + j][ty];
    *(half4v*)(dst + zo + (size_t)(n0 + ty) * K + k0 + tx * 4) = o;
}

// --- unified double-buffered MFMA GEMM with XCD-aware tile swizzle.
// C[M,N] = act(A[M,K] @ Bt[N,K]^T + bias). 256 thr = 4 waves (2x2). BK=32.
// LDS fragment order (conflict-free, 16B chunks); 1D grid of Mt*Nt blocks.
// Swizzle (when Mt%8==0 && Nt%8==0): XCD k = bid&7 owns n-band [k*Nt/8, ...);
// within the band, walk 8x8 super-tiles (m fast) so co-resident blocks on one
// XCD touch ~2MB A + ~2MB B — inside its private 4MB L2.
template <int TM, int TN, int DO_RELU, int OUT_F16>
__launch_bounds__(256, (TM == 128 ? 2 : 4))
__global__ void dgemm(const _Float16* __restrict__ A, const _Float16* __restrict__ Bt,
                      const void* __restrict__ bias_raw, void* __restrict__ Cout,
                      const int* __restrict__ flagp, int N, int K, int Mt, int Nt) {
    constexpr int BK = 32;
    constexpr int MI = TM / 64, NI = TN / 64;      // accs per wave (wave tile TM/2 x TN/2)
    constexpr int ACH = TM * BK / 8;               // 16B chunks per A stage
    constexpr int BCH = TN * BK / 8;
    constexpr int AT = ACH / 256, BT = BCH / 256;  // chunks per thread
    __shared__ _Float16 As[2 * ACH * 8];
    __shared__ _Float16 Bs[2 * BCH * 8];

    const int tid = threadIdx.x;
    const int lane = tid & 63;
    const int w = tid >> 6, wr = w >> 1, wc = w & 1;

    // --- XCD-aware swizzle ---
    int mt, nt;
    {
        const int bid = blockIdx.x;
        if ((Mt & 7) == 0 && (Nt & 7) == 0) {
            const int xcd = bid & 7, loc = bid >> 3;
            const int Bn = Nt >> 3;               // n-tiles per XCD band
            const int sr = loc / (8 * Bn);        // super-row of 8 m-tiles
            const int rem = loc - sr * (8 * Bn);
            mt = sr * 8 + (rem & 7);
            nt = xcd * Bn + (rem >> 3);
        } else {
            mt = bid % Mt;
            nt = bid / Mt;
        }
    }
    const int m0 = mt * TM, n0 = nt * TN;

    // staging chunk decode
    const _Float16* gAsrc[AT];
    _Float16* lAdst[AT];
#pragma unroll
    for (int t = 0; t < AT; ++t) {
        const int c = t * 256 + tid;
        const int ks = c / (TM * 2), rem = c % (TM * 2);
        const int row = (rem >> 6) * 32 + (rem & 31);
        const int kcol = ks * 16 + ((rem >> 5) & 1) * 8;
        gAsrc[t] = A + (size_t)(m0 + row) * K + kcol;
        lAdst[t] = As + c * 8;
    }
    const _Float16* gBsrc[BT];
    _Float16* lBdst[BT];
#pragma unroll
    for (int t = 0; t < BT; ++t) {
        const int c = t * 256 + tid;
        const int ks = c / (TN * 2), rem = c % (TN * 2);
        const int row = (rem >> 6) * 32 + (rem & 31);
        const int kcol = ks * 16 + ((rem >> 5) & 1) * 8;
        gBsrc[t] = Bt + (size_t)(n0 + row) * K + kcol;
        lBdst[t] = Bs + c * 8;
    }

    auto issue = [&](int k0, int st) {
#pragma unroll
        for (int t = 0; t < AT; ++t) gl_lds16(gAsrc[t] + k0, lAdst[t] + st * ACH * 8);
#pragma unroll
        for (int t = 0; t < BT; ++t) gl_lds16(gBsrc[t] + k0, lBdst[t] + st * BCH * 8);
    };

    floatx16 acc[MI][NI];
#pragma unroll
    for (int mi = 0; mi < MI; ++mi)
#pragma unroll
        for (int ni = 0; ni < NI; ++ni)
#pragma unroll
            for (int i = 0; i < 16; ++i) acc[mi][ni][i] = 0.f;

    auto compute = [&](int st) {
#pragma unroll
        for (int ks = 0; ks < 2; ++ks) {
            half8 af[MI], bf[NI];
#pragma unroll
            for (int mi = 0; mi < MI; ++mi)
                af[mi] = *(const half8*)(As + st * ACH * 8 + ((size_t)(ks * TM * 2 + (wr * MI + mi) * 64 + lane)) * 8);
#pragma unroll
            for (int ni = 0; ni < NI; ++ni)
                bf[ni] = *(const half8*)(Bs + st * BCH * 8 + ((size_t)(ks * TN * 2 + (wc * NI + ni) * 64 + lane)) * 8);
#pragma unroll
            for (int mi = 0; mi < MI; ++mi)
#pragma unroll
                for (int ni = 0; ni < NI; ++ni)
                    acc[mi][ni] = __builtin_amdgcn_mfma_f32_32x32x16_f16(af[mi], bf[ni], acc[mi][ni], 0, 0, 0);
        }
    };

    issue(0, 0);
    for (int k0 = 0; k0 < K; k0 += 2 * BK) {
        __syncthreads();                       // stage0 loads complete; stage1 free
        if (k0 + BK < K) issue(k0 + BK, 1);    // prefetch overlaps compute(0)
        compute(0);
        __syncthreads();                       // stage1 loads complete; stage0 free
        if (k0 + 2 * BK < K) issue(k0 + 2 * BK, 0);
        compute(1);
    }

    const int bf_ = *flagp;
    const int am = lane & 31;
    const int half = lane >> 5;
#pragma unroll
    for (int mi = 0; mi < MI; ++mi)
#pragma unroll
        for (int ni = 0; ni < NI; ++ni) {
            const int Rb = m0 + (wr * MI + mi) * 32;
            const int Cb = n0 + (wc * NI + ni) * 32 + am;
            const float bv = ldraw(bias_raw, Cb, bf_);
#pragma unroll
            for (int rr = 0; rr < 16; ++rr) {
                const int row = Rb + (rr & 3) + 8 * (rr >> 2) + 4 * half;
                float x = acc[mi][ni][rr] + bv;
                if (DO_RELU) x = fmaxf(x, 0.f);
                if (OUT_F16) ((_Float16*)Cout)[(size_t)row * N + Cb] = (_Float16)x;
                else ((float*)Cout)[(size_t)row * N + Cb] = x;
            }
        }
}

// --- fused: tanh(z) -> ||c-a|| -> softmax(-dist) . values, one block per b
// NOTE: z already includes the bexp bias (added in the expert GEMM epilogue).
__launch_bounds__(256)
__global__ void final_fused(const _Float16* __restrict__ z, const void* __restrict__ a_raw,
                            const float* __restrict__ values, const int* __restrict__ flag,
                            void* __restrict__ out) {
    const int b = blockIdx.x;
    const int n = threadIdx.x;
    const int bf = *flag;
    __shared__ float as_[32];
    if (n < 32) as_[n] = ldraw(a_raw, (size_t)b * kA + n, bf);
    __syncthreads();

    const _Float16* zp = z + (size_t)b * (kN * kA) + n * kA;
    float zl[32];
#pragma unroll
    for (int t = 0; t < 4; ++t) {
        half8 h = *(const half8*)(zp + t * 8);
#pragma unroll
        for (int j = 0; j < 8; ++j) zl[t * 8 + j] = (float)h[j];
    }
    float sum = 0.f;
#pragma unroll
    for (int a = 0; a < 32; ++a) {
        const float c = fast_tanh(zl[a]);  // MAX_A=1; bexp already in z
        const float d = c - as_[a];
        sum = fmaf(d, d, sum);
    }
    const float dist = sqrtf(sum + 0.01f);
    const float v = values[(size_t)b * kN + n];

    const int wid = n >> 6, lane = n & 63;
    __shared__ float red[8];
    __shared__ float rw[4], rwv[4];
    float m = dist;
    for (int off = 32; off > 0; off >>= 1) m = fminf(m, __shfl_down(m, off));
    if (lane == 0) red[wid] = m;
    __syncthreads();
    if (n == 0) red[4] = fminf(fminf(red[0], red[1]), fminf(red[2], red[3]));
    __syncthreads();
    const float dmin = red[4];

    float wgt = expf(dmin - dist);
    float wv = wgt * v;
    for (int off = 32; off > 0; off >>= 1) {
        wgt += __shfl_down(wgt, off);
        wv += __shfl_down(wv, off);
    }
    if (lane == 0) { rw[wid] = wgt; rwv[wid] = wv; }
    __syncthreads();
    if (n == 0) {
        const float sw = rw[0] + rw[1] + rw[2] + rw[3];
        const float swv = rwv[0] + rwv[1] + rwv[2] + rwv[3];
        const float o = swv / sw;
        if (bf) ((__hip_bfloat16*)out)[b] = __float2bfloat16(o);
        else    ((float*)out)[b] = o;
    }
}

extern "C" void kernel_launch(void* const* d_in, const int* in_sizes, int n_in,
                              void* d_out, int out_size, void* d_ws, size_t ws_size,
                              hipStream_t stream) {
    (void)in_sizes; (void)n_in; (void)out_size; (void)ws_size;
    char* ws = (char*)d_ws;
    int* flag = (int*)(ws + OFF_FLAG);
    _Float16* s16   = (_Float16*)(ws + OFF_S16);
    _Float16* wv1t  = (_Float16*)(ws + OFF_WV1T);
    _Float16* wv2t  = (_Float16*)(ws + OFF_WV2T);
    _Float16* wv3t  = (_Float16*)(ws + OFF_WV3T);
    _Float16* wv4t  = (_Float16*)(ws + OFF_WV4T);
    _Float16* wl1t  = (_Float16*)(ws + OFF_WL1T);
    _Float16* wexpt = (_Float16*)(ws + OFF_WEXPT);
    _Float16* buf1  = (_Float16*)(ws + OFF_BUF1);
    _Float16* buf2  = (_Float16*)(ws + OFF_BUF2);
    float* values   = (float*)(ws + OFF_VAL);
    _Float16* z     = (_Float16*)(ws + OFF_Z);

    detect_kernel<<<1, 256, 0, stream>>>((const unsigned int*)d_in[0], flag);
    convert_to_f16<<<512, 256, 0, stream>>>(d_in[0], s16, kB * kS, flag);

    TPack tp;
    tp.d[0] = {d_in[2],  wv1t,  kS, kH, (kH / 32) * (kS / 32)};          // 128
    tp.d[1] = {d_in[4],  wv2t,  kH, kH, (kH / 32) * (kH / 32)};          // 1024
    tp.d[2] = {d_in[6],  wv3t,  kH, kH, (kH / 32) * (kH / 32)};          // 1024
    tp.d[3] = {d_in[8],  wv4t,  kH, kN, (kN / 32) * (kH / 32)};          // 256
    tp.d[4] = {d_in[10], wl1t,  kS, kH, (kH / 32) * (kS / 32)};          // 128
    tp.d[5] = {d_in[12], wexpt, kH, kA, kN * (kA / 32) * (kH / 32)};     // 8192
    int total_tiles = 0;
    for (int i = 0; i < 6; ++i) total_tiles += tp.d[i].tiles;            // 10752
    transpose_all<<<total_tiles, dim3(8, 32), 0, stream>>>(tp, flag);

    // value MLP (1D grids, swizzled inside)
    dgemm<64, 64, 1, 1><<<(kB / 64) * (kH / 64), 256, 0, stream>>>(s16,  wv1t, d_in[3], buf1, flag, kH, kS, kB / 64, kH / 64);
    dgemm<128, 64, 1, 1><<<(kB / 128) * (kH / 64), 256, 0, stream>>>(buf1, wv2t, d_in[5], buf2, flag, kH, kH, kB / 128, kH / 64);
    dgemm<128, 64, 1, 1><<<(kB / 128) * (kH / 64), 256, 0, stream>>>(buf2, wv3t, d_in[7], buf1, flag, kH, kH, kB / 128, kH / 64);
    dgemm<64, 64, 0, 0><<<(kB / 64) * (kN / 64), 256, 0, stream>>>(buf1, wv4t, d_in[9], values, flag, kN, kH, kB / 64, kN / 64);
    // location hidden
    dgemm<64, 64, 1, 1><<<(kB / 64) * (kH / 64), 256, 0, stream>>>(s16,  wl1t, d_in[11], buf2, flag, kH, kS, kB / 64, kH / 64);
    // expert heads: z[B, N*A] = buf2 @ wexpt^T + bexp (bias added HERE, once)
    dgemm<128, 128, 0, 1><<<(kB / 128) * ((kN * kA) / 128), 256, 0, stream>>>(buf2, wexpt, d_in[13], z, flag, kN * kA, kH, kB / 128, (kN * kA) / 128);
    // fused tanh + distance + softmax + value readout
    final_fused<<<kB, 256, 0, stream>>>(z, d_in[1], values, flag, d_out);
}

// Round 10
// 322.155 us; speedup vs baseline: 1.0823x; 1.0757x over previous
//
#include <hip/hip_runtime.h>
#include <hip/hip_bf16.h>

// Net_40089224741482 round 10: bytes-per-FLOP test.
//  r4-r9: every loop-shape variant pins expert GEMM at ~145us = ~7.4 TB/s staging
//  service => per-CU staging-bandwidth wall. Lever: bigger tile = fewer bytes/FLOP.
//  Expert: TM=256xTN=128, 512 thr (8 waves 4x2, wave tile 64x64), BK=32 dbuf,
//  LDS 48KB, 85.3 FLOP/staged-byte (was 64). Others unchanged.

typedef _Float16 half8 __attribute__((ext_vector_type(8)));
typedef _Float16 half4v __attribute__((ext_vector_type(4)));
typedef float floatx16 __attribute__((ext_vector_type(16)));

namespace {
constexpr int kB = 4096, kS = 128, kA = 32, kH = 1024, kN = 256;
constexpr size_t al(size_t x) { return (x + 255) & ~size_t(255); }
// layout: FLAG | S16 | WEXPT | BUF2 | VAL | [weights+BUF1 region, aliased by Z]
constexpr size_t OFF_FLAG  = 0;
constexpr size_t OFF_S16   = 256;
constexpr size_t OFF_WEXPT = OFF_S16   + al((size_t)kB * kS * 2);
constexpr size_t OFF_BUF2  = OFF_WEXPT + al((size_t)kN * kA * kH * 2);
constexpr size_t OFF_VAL   = OFF_BUF2  + al((size_t)kB * kH * 2);
constexpr size_t OFF_WV1T  = OFF_VAL   + al((size_t)kB * kN * 4);
constexpr size_t OFF_WV2T  = OFF_WV1T  + al((size_t)kS * kH * 2);
constexpr size_t OFF_WV3T  = OFF_WV2T  + al((size_t)kH * kH * 2);
constexpr size_t OFF_WV4T  = OFF_WV3T  + al((size_t)kH * kH * 2);
constexpr size_t OFF_WL1T  = OFF_WV4T  + al((size_t)kH * kN * 2);
constexpr size_t OFF_BUF1  = OFF_WL1T  + al((size_t)kS * kH * 2);
constexpr size_t OFF_Z     = OFF_WV1T;  // aliases weights+BUF1 (all dead before Z written)
} // namespace

__device__ __forceinline__ float ldraw(const void* p, size_t i, int bf) {
    if (bf) return __uint_as_float(((unsigned)((const unsigned short*)p)[i]) << 16);
    return ((const float*)p)[i];
}

__device__ __forceinline__ float4 ldraw4(const void* p, size_t i, int bf) {
    if (bf) {
        ushort4 u = *(const ushort4*)((const unsigned short*)p + i);
        return make_float4(__uint_as_float((unsigned)u.x << 16),
                           __uint_as_float((unsigned)u.y << 16),
                           __uint_as_float((unsigned)u.z << 16),
                           __uint_as_float((unsigned)u.w << 16));
    }
    return *(const float4*)((const float*)p + i);
}

__device__ __forceinline__ void gl_lds16(const _Float16* g, _Float16* l) {
    __builtin_amdgcn_global_load_lds(
        (const __attribute__((address_space(1))) unsigned int*)g,
        (__attribute__((address_space(3))) unsigned int*)l, 16, 0, 0);
}

__device__ __forceinline__ float fast_tanh(float x) {
    x = fminf(9.f, fmaxf(-9.f, x));
    float e = __expf(2.f * x);
    return (e - 1.f) * __builtin_amdgcn_rcpf(e + 1.f);
}

// --- dtype detection, parallel: low 16 bits of fp32 N(0,1) are uniform mantissa
// bits; for packed bf16 they are a bf16 value whose exponent sits near 127.
__global__ void detect_kernel(const unsigned int* __restrict__ s_raw, int* __restrict__ flag) {
    __shared__ int cnt;
    if (threadIdx.x == 0) cnt = 0;
    __syncthreads();
    const unsigned e = (s_raw[threadIdx.x] >> 7) & 0xFFu;
    int c = (e >= 118u && e <= 135u) ? 1 : 0;
    for (int off = 32; off > 0; off >>= 1) c += __shfl_down(c, off);
    if ((threadIdx.x & 63) == 0) atomicAdd(&cnt, c);
    __syncthreads();
    if (threadIdx.x == 0) *flag = (cnt > 128) ? 1 : 0;
}

__global__ void convert_to_f16(const void* __restrict__ src, _Float16* __restrict__ dst,
                               int n, const int* __restrict__ flag) {
    const int bf = *flag;
    int i = blockIdx.x * blockDim.x + threadIdx.x;
    const int stride = gridDim.x * blockDim.x;
    for (; i < n; i += stride) dst[i] = (_Float16)ldraw(src, i, bf);
}

// --- ALL weight transposes in one dispatch: src [Z][K][N] -> dst [Z][N][K] f16
struct TDesc { const void* src; _Float16* dst; int K; int N; int tiles; };
struct TPack { TDesc d[6]; };

__global__ void transpose_all(TPack p, const int* __restrict__ flag) {
    __shared__ float tile[32][33];
    const int bf = *flag;
    int bid = blockIdx.x;
    int i = 0;
    while (bid >= p.d[i].tiles) { bid -= p.d[i].tiles; ++i; }
    const int K = p.d[i].K, N = p.d[i].N;
    const int tpz = (N >> 5) * (K >> 5);
    const int z = bid / tpz, r = bid - z * tpz;
    const int n0 = (r % (N >> 5)) * 32, k0 = (r / (N >> 5)) * 32;
    const size_t zo = (size_t)z * K * N;
    const void* src = p.d[i].src;
    _Float16* dst = p.d[i].dst;
    const int tx = threadIdx.x, ty = threadIdx.y;  // tx 0..7, ty 0..31
    float4 v = ldraw4(src, zo + (size_t)(k0 + ty) * N + n0 + tx * 4, bf);
    tile[ty][tx * 4 + 0] = v.x;
    tile[ty][tx * 4 + 1] = v.y;
    tile[ty][tx * 4 + 2] = v.z;
    tile[ty][tx * 4 + 3] = v.w;
    __syncthreads();
    half4v o;
#pragma unroll
    for (int j = 0; j < 4; ++j) o[j] = (_Float16)tile[tx * 4 + j][ty];
    *(half4v*)(dst + zo + (size_t)(n0 + ty) * K + k0 + tx * 4) = o;
}

// --- unified double-buffered MFMA GEMM, wave-grid templated.
// C[M,N] = act(A[M,K] @ Bt[N,K]^T + bias). WM*WN waves; wave tile (TM/WM)x(TN/WN)
// as MIxNI 32x32x16 accs. BK=32, LDS fragment order (conflict-free 16B chunks),
// global_load_lds w16, dbuf one barrier per stage. 1D grid + XCD swizzle.
template <int TM, int TN, int WM, int WN, int DO_RELU, int OUT_F16>
__launch_bounds__(WM * WN * 64, 2)
__global__ void dgemm(const _Float16* __restrict__ A, const _Float16* __restrict__ Bt,
                      const void* __restrict__ bias_raw, void* __restrict__ Cout,
                      const int* __restrict__ flagp, int N, int K, int Mt, int Nt) {
    constexpr int NT = WM * WN * 64;
    constexpr int BK = 32;
    constexpr int MI = TM / WM / 32, NI = TN / WN / 32;
    constexpr int ACH = TM * BK / 8;               // 16B chunks per A stage
    constexpr int BCH = TN * BK / 8;
    constexpr int AT = ACH / NT, BT = BCH / NT;    // chunks per thread
    __shared__ _Float16 As[2 * ACH * 8];
    __shared__ _Float16 Bs[2 * BCH * 8];

    const int tid = threadIdx.x;
    const int lane = tid & 63;
    const int w = tid >> 6, wr = w / WN, wc = w % WN;

    // --- XCD-aware swizzle ---
    int mt, nt;
    {
        const int bid = blockIdx.x;
        if ((Mt & 7) == 0 && (Nt & 7) == 0) {
            const int xcd = bid & 7, loc = bid >> 3;
            const int Bn = Nt >> 3;               // n-tiles per XCD band
            const int sr = loc / (8 * Bn);        // super-row of 8 m-tiles
            const int rem = loc - sr * (8 * Bn);
            mt = sr * 8 + (rem & 7);
            nt = xcd * Bn + (rem >> 3);
        } else {
            mt = bid % Mt;
            nt = bid / Mt;
        }
    }
    const int m0 = mt * TM, n0 = nt * TN;

    // staging chunk decode: chunk c -> ks = c/(T*2); rem = c%(T*2);
    // row = (rem>>6)*32 + (rem&31); kcol = ks*16 + ((rem>>5)&1)*8
    const _Float16* gAsrc[AT];
    _Float16* lAdst[AT];
#pragma unroll
    for (int t = 0; t < AT; ++t) {
        const int c = t * NT + tid;
        const int ks = c / (TM * 2), rem = c % (TM * 2);
        const int row = (rem >> 6) * 32 + (rem & 31);
        const int kcol = ks * 16 + ((rem >> 5) & 1) * 8;
        gAsrc[t] = A + (size_t)(m0 + row) * K + kcol;
        lAdst[t] = As + c * 8;
    }
    const _Float16* gBsrc[BT];
    _Float16* lBdst[BT];
#pragma unroll
    for (int t = 0; t < BT; ++t) {
        const int c = t * NT + tid;
        const int ks = c / (TN * 2), rem = c % (TN * 2);
        const int row = (rem >> 6) * 32 + (rem & 31);
        const int kcol = ks * 16 + ((rem >> 5) & 1) * 8;
        gBsrc[t] = Bt + (size_t)(n0 + row) * K + kcol;
        lBdst[t] = Bs + c * 8;
    }

    auto issue = [&](int k0, int st) {
#pragma unroll
        for (int t = 0; t < AT; ++t) gl_lds16(gAsrc[t] + k0, lAdst[t] + st * ACH * 8);
#pragma unroll
        for (int t = 0; t < BT; ++t) gl_lds16(gBsrc[t] + k0, lBdst[t] + st * BCH * 8);
    };

    floatx16 acc[MI][NI];
#pragma unroll
    for (int mi = 0; mi < MI; ++mi)
#pragma unroll
        for (int ni = 0; ni < NI; ++ni)
#pragma unroll
            for (int i = 0; i < 16; ++i) acc[mi][ni][i] = 0.f;

    auto compute = [&](int st) {
#pragma unroll
        for (int ks = 0; ks < 2; ++ks) {
            half8 af[MI], bf[NI];
#pragma unroll
            for (int mi = 0; mi < MI; ++mi)
                af[mi] = *(const half8*)(As + st * ACH * 8 + ((size_t)(ks * TM * 2 + (wr * MI + mi) * 64 + lane)) * 8);
#pragma unroll
            for (int ni = 0; ni < NI; ++ni)
                bf[ni] = *(const half8*)(Bs + st * BCH * 8 + ((size_t)(ks * TN * 2 + (wc * NI + ni) * 64 + lane)) * 8);
#pragma unroll
            for (int mi = 0; mi < MI; ++mi)
#pragma unroll
                for (int ni = 0; ni < NI; ++ni)
                    acc[mi][ni] = __builtin_amdgcn_mfma_f32_32x32x16_f16(af[mi], bf[ni], acc[mi][ni], 0, 0, 0);
        }
    };

    issue(0, 0);
    for (int k0 = 0; k0 < K; k0 += 2 * BK) {
        __syncthreads();                       // stage0 loads complete; stage1 free
        if (k0 + BK < K) issue(k0 + BK, 1);    // prefetch overlaps compute(0)
        compute(0);
        __syncthreads();                       // stage1 loads complete; stage0 free
        if (k0 + 2 * BK < K) issue(k0 + 2 * BK, 0);
        compute(1);
    }

    const int bf_ = *flagp;
    const int am = lane & 31;
    const int half = lane >> 5;
#pragma unroll
    for (int mi = 0; mi < MI; ++mi)
#pragma unroll
        for (int ni = 0; ni < NI; ++ni) {
            const int Rb = m0 + (wr * MI + mi) * 32;
            const int Cb = n0 + (wc * NI + ni) * 32 + am;
            const float bv = ldraw(bias_raw, Cb, bf_);
#pragma unroll
            for (int rr = 0; rr < 16; ++rr) {
                const int row = Rb + (rr & 3) + 8 * (rr >> 2) + 4 * half;
                float x = acc[mi][ni][rr] + bv;
                if (DO_RELU) x = fmaxf(x, 0.f);
                if (OUT_F16) ((_Float16*)Cout)[(size_t)row * N + Cb] = (_Float16)x;
                else ((float*)Cout)[(size_t)row * N + Cb] = x;
            }
        }
}

// --- fused: tanh(z) -> ||c-a|| -> softmax(-dist) . values, one block per b
// NOTE: z already includes the bexp bias (added in the expert GEMM epilogue).
__launch_bounds__(256)
__global__ void final_fused(const _Float16* __restrict__ z, const void* __restrict__ a_raw,
                            const float* __restrict__ values, const int* __restrict__ flag,
                            void* __restrict__ out) {
    const int b = blockIdx.x;
    const int n = threadIdx.x;
    const int bf = *flag;
    __shared__ float as_[32];
    if (n < 32) as_[n] = ldraw(a_raw, (size_t)b * kA + n, bf);
    __syncthreads();

    const _Float16* zp = z + (size_t)b * (kN * kA) + n * kA;
    float zl[32];
#pragma unroll
    for (int t = 0; t < 4; ++t) {
        half8 h = *(const half8*)(zp + t * 8);
#pragma unroll
        for (int j = 0; j < 8; ++j) zl[t * 8 + j] = (float)h[j];
    }
    float sum = 0.f;
#pragma unroll
    for (int a = 0; a < 32; ++a) {
        const float c = fast_tanh(zl[a]);  // MAX_A=1; bexp already in z
        const float d = c - as_[a];
        sum = fmaf(d, d, sum);
    }
    const float dist = sqrtf(sum + 0.01f);
    const float v = values[(size_t)b * kN + n];

    const int wid = n >> 6, lane = n & 63;
    __shared__ float red[8];
    __shared__ float rw[4], rwv[4];
    float m = dist;
    for (int off = 32; off > 0; off >>= 1) m = fminf(m, __shfl_down(m, off));
    if (lane == 0) red[wid] = m;
    __syncthreads();
    if (n == 0) red[4] = fminf(fminf(red[0], red[1]), fminf(red[2], red[3]));
    __syncthreads();
    const float dmin = red[4];

    float wgt = expf(dmin - dist);
    float wv = wgt * v;
    for (int off = 32; off > 0; off >>= 1) {
        wgt += __shfl_down(wgt, off);
        wv += __shfl_down(wv, off);
    }
    if (lane == 0) { rw[wid] = wgt; rwv[wid] = wv; }
    __syncthreads();
    if (n == 0) {
        const float sw = rw[0] + rw[1] + rw[2] + rw[3];
        const float swv = rwv[0] + rwv[1] + rwv[2] + rwv[3];
        const float o = swv / sw;
        if (bf) ((__hip_bfloat16*)out)[b] = __float2bfloat16(o);
        else    ((float*)out)[b] = o;
    }
}

extern "C" void kernel_launch(void* const* d_in, const int* in_sizes, int n_in,
                              void* d_out, int out_size, void* d_ws, size_t ws_size,
                              hipStream_t stream) {
    (void)in_sizes; (void)n_in; (void)out_size; (void)ws_size;
    char* ws = (char*)d_ws;
    int* flag = (int*)(ws + OFF_FLAG);
    _Float16* s16   = (_Float16*)(ws + OFF_S16);
    _Float16* wv1t  = (_Float16*)(ws + OFF_WV1T);
    _Float16* wv2t  = (_Float16*)(ws + OFF_WV2T);
    _Float16* wv3t  = (_Float16*)(ws + OFF_WV3T);
    _Float16* wv4t  = (_Float16*)(ws + OFF_WV4T);
    _Float16* wl1t  = (_Float16*)(ws + OFF_WL1T);
    _Float16* wexpt = (_Float16*)(ws + OFF_WEXPT);
    _Float16* buf1  = (_Float16*)(ws + OFF_BUF1);
    _Float16* buf2  = (_Float16*)(ws + OFF_BUF2);
    float* values   = (float*)(ws + OFF_VAL);
    _Float16* z     = (_Float16*)(ws + OFF_Z);

    detect_kernel<<<1, 256, 0, stream>>>((const unsigned int*)d_in[0], flag);
    convert_to_f16<<<512, 256, 0, stream>>>(d_in[0], s16, kB * kS, flag);

    TPack tp;
    tp.d[0] = {d_in[2],  wv1t,  kS, kH, (kH / 32) * (kS / 32)};          // 128
    tp.d[1] = {d_in[4],  wv2t,  kH, kH, (kH / 32) * (kH / 32)};          // 1024
    tp.d[2] = {d_in[6],  wv3t,  kH, kH, (kH / 32) * (kH / 32)};          // 1024
    tp.d[3] = {d_in[8],  wv4t,  kH, kN, (kN / 32) * (kH / 32)};          // 256
    tp.d[4] = {d_in[10], wl1t,  kS, kH, (kH / 32) * (kS / 32)};          // 128
    tp.d[5] = {d_in[12], wexpt, kH, kA, kN * (kA / 32) * (kH / 32)};     // 8192
    int total_tiles = 0;
    for (int i = 0; i < 6; ++i) total_tiles += tp.d[i].tiles;            // 10752
    transpose_all<<<total_tiles, dim3(8, 32), 0, stream>>>(tp, flag);

    // value MLP (1D grids, swizzled inside)
    dgemm<64, 64, 2, 2, 1, 1><<<(kB / 64) * (kH / 64), 256, 0, stream>>>(s16,  wv1t, d_in[3], buf1, flag, kH, kS, kB / 64, kH / 64);
    dgemm<128, 64, 2, 2, 1, 1><<<(kB / 128) * (kH / 64), 256, 0, stream>>>(buf1, wv2t, d_in[5], buf2, flag, kH, kH, kB / 128, kH / 64);
    dgemm<128, 64, 2, 2, 1, 1><<<(kB / 128) * (kH / 64), 256, 0, stream>>>(buf2, wv3t, d_in[7], buf1, flag, kH, kH, kB / 128, kH / 64);
    dgemm<64, 64, 2, 2, 0, 0><<<(kB / 64) * (kN / 64), 256, 0, stream>>>(buf1, wv4t, d_in[9], values, flag, kN, kH, kB / 64, kN / 64);
    // location hidden
    dgemm<64, 64, 2, 2, 1, 1><<<(kB / 64) * (kH / 64), 256, 0, stream>>>(s16,  wl1t, d_in[11], buf2, flag, kH, kS, kB / 64, kH / 64);
    // expert heads: z[B, N*A] = buf2 @ wexpt^T + bexp; 256x128 tile, 512 thr
    dgemm<256, 128, 4, 2, 0, 1><<<(kB / 256) * ((kN * kA) / 128), 512, 0, stream>>>(buf2, wexpt, d_in[13], z, flag, kN * kA, kH, kB / 256, (kN * kA) / 128);
    // fused tanh + distance + softmax + value readout
    final_fused<<<kB, 256, 0, stream>>>(z, d_in[1], values, flag, d_out);
}

// Round 12
// 315.312 us; speedup vs baseline: 1.1057x; 1.0217x over previous
//
#include <hip/hip_runtime.h>
#include <hip/hip_bf16.h>

// Net_40089224741482 round 12 (= r11 plan, compile-fixed):
//  - staging arrays ceil-divided + guarded (no zero-length arrays)
//  - expert: 256x256 tile via 1024 thr (16 waves 4x4, wave 64x64, 4 accs) ->
//    512 MB staged (134 FLOP/byte), ~116 VGPR keeps 4 waves/SIMD occupancy
//  - gemm2/3: 128x128 (128 MB staged, 256 blocks)

typedef _Float16 half8 __attribute__((ext_vector_type(8)));
typedef _Float16 half4v __attribute__((ext_vector_type(4)));
typedef float floatx16 __attribute__((ext_vector_type(16)));

namespace {
constexpr int kB = 4096, kS = 128, kA = 32, kH = 1024, kN = 256;
constexpr size_t al(size_t x) { return (x + 255) & ~size_t(255); }
// layout: FLAG | S16 | WEXPT | BUF2 | VAL | [weights+BUF1 region, aliased by Z]
constexpr size_t OFF_FLAG  = 0;
constexpr size_t OFF_S16   = 256;
constexpr size_t OFF_WEXPT = OFF_S16   + al((size_t)kB * kS * 2);
constexpr size_t OFF_BUF2  = OFF_WEXPT + al((size_t)kN * kA * kH * 2);
constexpr size_t OFF_VAL   = OFF_BUF2  + al((size_t)kB * kH * 2);
constexpr size_t OFF_WV1T  = OFF_VAL   + al((size_t)kB * kN * 4);
constexpr size_t OFF_WV2T  = OFF_WV1T  + al((size_t)kS * kH * 2);
constexpr size_t OFF_WV3T  = OFF_WV2T  + al((size_t)kH * kH * 2);
constexpr size_t OFF_WV4T  = OFF_WV3T  + al((size_t)kH * kH * 2);
constexpr size_t OFF_WL1T  = OFF_WV4T  + al((size_t)kH * kN * 2);
constexpr size_t OFF_BUF1  = OFF_WL1T  + al((size_t)kS * kH * 2);
constexpr size_t OFF_Z     = OFF_WV1T;  // aliases weights+BUF1 (all dead before Z written)
} // namespace

__device__ __forceinline__ float ldraw(const void* p, size_t i, int bf) {
    if (bf) return __uint_as_float(((unsigned)((const unsigned short*)p)[i]) << 16);
    return ((const float*)p)[i];
}

__device__ __forceinline__ float4 ldraw4(const void* p, size_t i, int bf) {
    if (bf) {
        ushort4 u = *(const ushort4*)((const unsigned short*)p + i);
        return make_float4(__uint_as_float((unsigned)u.x << 16),
                           __uint_as_float((unsigned)u.y << 16),
                           __uint_as_float((unsigned)u.z << 16),
                           __uint_as_float((unsigned)u.w << 16));
    }
    return *(const float4*)((const float*)p + i);
}

__device__ __forceinline__ void gl_lds16(const _Float16* g, _Float16* l) {
    __builtin_amdgcn_global_load_lds(
        (const __attribute__((address_space(1))) unsigned int*)g,
        (__attribute__((address_space(3))) unsigned int*)l, 16, 0, 0);
}

__device__ __forceinline__ float fast_tanh(float x) {
    x = fminf(9.f, fmaxf(-9.f, x));
    float e = __expf(2.f * x);
    return (e - 1.f) * __builtin_amdgcn_rcpf(e + 1.f);
}

// --- dtype detection, parallel: low 16 bits of fp32 N(0,1) are uniform mantissa
// bits; for packed bf16 they are a bf16 value whose exponent sits near 127.
__global__ void detect_kernel(const unsigned int* __restrict__ s_raw, int* __restrict__ flag) {
    __shared__ int cnt;
    if (threadIdx.x == 0) cnt = 0;
    __syncthreads();
    const unsigned e = (s_raw[threadIdx.x] >> 7) & 0xFFu;
    int c = (e >= 118u && e <= 135u) ? 1 : 0;
    for (int off = 32; off > 0; off >>= 1) c += __shfl_down(c, off);
    if ((threadIdx.x & 63) == 0) atomicAdd(&cnt, c);
    __syncthreads();
    if (threadIdx.x == 0) *flag = (cnt > 128) ? 1 : 0;
}

__global__ void convert_to_f16(const void* __restrict__ src, _Float16* __restrict__ dst,
                               int n, const int* __restrict__ flag) {
    const int bf = *flag;
    int i = blockIdx.x * blockDim.x + threadIdx.x;
    const int stride = gridDim.x * blockDim.x;
    for (; i < n; i += stride) dst[i] = (_Float16)ldraw(src, i, bf);
}

// --- ALL weight transposes in one dispatch: src [Z][K][N] -> dst [Z][N][K] f16
struct TDesc { const void* src; _Float16* dst; int K; int N; int tiles; };
struct TPack { TDesc d[6]; };

__global__ void transpose_all(TPack p, const int* __restrict__ flag) {
    __shared__ float tile[32][33];
    const int bf = *flag;
    int bid = blockIdx.x;
    int i = 0;
    while (bid >= p.d[i].tiles) { bid -= p.d[i].tiles; ++i; }
    const int K = p.d[i].K, N = p.d[i].N;
    const int tpz = (N >> 5) * (K >> 5);
    const int z = bid / tpz, r = bid - z * tpz;
    const int n0 = (r % (N >> 5)) * 32, k0 = (r / (N >> 5)) * 32;
    const size_t zo = (size_t)z * K * N;
    const void* src = p.d[i].src;
    _Float16* dst = p.d[i].dst;
    const int tx = threadIdx.x, ty = threadIdx.y;  // tx 0..7, ty 0..31
    float4 v = ldraw4(src, zo + (size_t)(k0 + ty) * N + n0 + tx * 4, bf);
    tile[ty][tx * 4 + 0] = v.x;
    tile[ty][tx * 4 + 1] = v.y;
    tile[ty][tx * 4 + 2] = v.z;
    tile[ty][tx * 4 + 3] = v.w;
    __syncthreads();
    half4v o;
#pragma unroll
    for (int j = 0; j < 4; ++j) o[j] = (_Float16)tile[tx * 4 + j][ty];
    *(half4v*)(dst + zo + (size_t)(n0 + ty) * K + k0 + tx * 4) = o;
}

// --- unified double-buffered MFMA GEMM, wave-grid templated.
// C[M,N] = act(A[M,K] @ Bt[N,K]^T + bias). WM*WN waves; wave tile (TM/WM)x(TN/WN)
// as MIxNI 32x32x16 accs. BK=32, LDS fragment order (conflict-free 16B chunks),
// global_load_lds w16, dbuf one barrier per stage. 1D grid + XCD swizzle.
// Staging arrays ceil-divided; tail threads guarded (folds away when exact).
template <int TM, int TN, int WM, int WN, int DO_RELU, int OUT_F16>
__launch_bounds__(WM * WN * 64, 2)
__global__ void dgemm(const _Float16* __restrict__ A, const _Float16* __restrict__ Bt,
                      const void* __restrict__ bias_raw, void* __restrict__ Cout,
                      const int* __restrict__ flagp, int N, int K, int Mt, int Nt) {
    constexpr int NT = WM * WN * 64;
    constexpr int BK = 32;
    constexpr int MI = TM / WM / 32, NI = TN / WN / 32;
    constexpr int ACH = TM * BK / 8;               // 16B chunks per A stage
    constexpr int BCH = TN * BK / 8;
    constexpr int AT = (ACH + NT - 1) / NT;        // chunks per thread (ceil)
    constexpr int BT = (BCH + NT - 1) / NT;
    __shared__ _Float16 As[2 * ACH * 8];
    __shared__ _Float16 Bs[2 * BCH * 8];

    const int tid = threadIdx.x;
    const int lane = tid & 63;
    const int w = tid >> 6, wr = w / WN, wc = w % WN;

    // --- XCD-aware swizzle ---
    int mt, nt;
    {
        const int bid = blockIdx.x;
        if ((Mt & 7) == 0 && (Nt & 7) == 0) {
            const int xcd = bid & 7, loc = bid >> 3;
            const int Bn = Nt >> 3;               // n-tiles per XCD band
            const int sr = loc / (8 * Bn);        // super-row of 8 m-tiles
            const int rem = loc - sr * (8 * Bn);
            mt = sr * 8 + (rem & 7);
            nt = xcd * Bn + (rem >> 3);
        } else {
            mt = bid % Mt;
            nt = bid / Mt;
        }
    }
    const int m0 = mt * TM, n0 = nt * TN;

    // staging chunk decode: chunk c -> ks = c/(T*2); rem = c%(T*2);
    // row = (rem>>6)*32 + (rem&31); kcol = ks*16 + ((rem>>5)&1)*8
    const _Float16* gAsrc[AT];
    _Float16* lAdst[AT];
#pragma unroll
    for (int t = 0; t < AT; ++t) {
        int c = t * NT + tid;
        if (c >= ACH) c = ACH - 1;  // clamped dummy; never issued
        const int ks = c / (TM * 2), rem = c % (TM * 2);
        const int row = (rem >> 6) * 32 + (rem & 31);
        const int kcol = ks * 16 + ((rem >> 5) & 1) * 8;
        gAsrc[t] = A + (size_t)(m0 + row) * K + kcol;
        lAdst[t] = As + c * 8;
    }
    const _Float16* gBsrc[BT];
    _Float16* lBdst[BT];
#pragma unroll
    for (int t = 0; t < BT; ++t) {
        int c = t * NT + tid;
        if (c >= BCH) c = BCH - 1;
        const int ks = c / (TN * 2), rem = c % (TN * 2);
        const int row = (rem >> 6) * 32 + (rem & 31);
        const int kcol = ks * 16 + ((rem >> 5) & 1) * 8;
        gBsrc[t] = Bt + (size_t)(n0 + row) * K + kcol;
        lBdst[t] = Bs + c * 8;
    }

    auto issue = [&](int k0, int st) {
#pragma unroll
        for (int t = 0; t < AT; ++t)
            if ((t + 1) * NT <= ACH || t * NT + tid < ACH)
                gl_lds16(gAsrc[t] + k0, lAdst[t] + st * ACH * 8);
#pragma unroll
        for (int t = 0; t < BT; ++t)
            if ((t + 1) * NT <= BCH || t * NT + tid < BCH)
                gl_lds16(gBsrc[t] + k0, lBdst[t] + st * BCH * 8);
    };

    floatx16 acc[MI][NI];
#pragma unroll
    for (int mi = 0; mi < MI; ++mi)
#pragma unroll
        for (int ni = 0; ni < NI; ++ni)
#pragma unroll
            for (int i = 0; i < 16; ++i) acc[mi][ni][i] = 0.f;

    auto compute = [&](int st) {
#pragma unroll
        for (int ks = 0; ks < 2; ++ks) {
            half8 af[MI], bf[NI];
#pragma unroll
            for (int mi = 0; mi < MI; ++mi)
                af[mi] = *(const half8*)(As + st * ACH * 8 + ((size_t)(ks * TM * 2 + (wr * MI + mi) * 64 + lane)) * 8);
#pragma unroll
            for (int ni = 0; ni < NI; ++ni)
                bf[ni] = *(const half8*)(Bs + st * BCH * 8 + ((size_t)(ks * TN * 2 + (wc * NI + ni) * 64 + lane)) * 8);
#pragma unroll
            for (int mi = 0; mi < MI; ++mi)
#pragma unroll
                for (int ni = 0; ni < NI; ++ni)
                    acc[mi][ni] = __builtin_amdgcn_mfma_f32_32x32x16_f16(af[mi], bf[ni], acc[mi][ni], 0, 0, 0);
        }
    };

    issue(0, 0);
    for (int k0 = 0; k0 < K; k0 += 2 * BK) {
        __syncthreads();                       // stage0 loads complete; stage1 free
        if (k0 + BK < K) issue(k0 + BK, 1);    // prefetch overlaps compute(0)
        compute(0);
        __syncthreads();                       // stage1 loads complete; stage0 free
        if (k0 + 2 * BK < K) issue(k0 + 2 * BK, 0);
        compute(1);
    }

    const int bf_ = *flagp;
    const int am = lane & 31;
    const int half = lane >> 5;
#pragma unroll
    for (int mi = 0; mi < MI; ++mi)
#pragma unroll
        for (int ni = 0; ni < NI; ++ni) {
            const int Rb = m0 + (wr * MI + mi) * 32;
            const int Cb = n0 + (wc * NI + ni) * 32 + am;
            const float bv = ldraw(bias_raw, Cb, bf_);
#pragma unroll
            for (int rr = 0; rr < 16; ++rr) {
                const int row = Rb + (rr & 3) + 8 * (rr >> 2) + 4 * half;
                float x = acc[mi][ni][rr] + bv;
                if (DO_RELU) x = fmaxf(x, 0.f);
                if (OUT_F16) ((_Float16*)Cout)[(size_t)row * N + Cb] = (_Float16)x;
                else ((float*)Cout)[(size_t)row * N + Cb] = x;
            }
        }
}

// --- fused: tanh(z) -> ||c-a|| -> softmax(-dist) . values, one block per b
// NOTE: z already includes the bexp bias (added in the expert GEMM epilogue).
__launch_bounds__(256)
__global__ void final_fused(const _Float16* __restrict__ z, const void* __restrict__ a_raw,
                            const float* __restrict__ values, const int* __restrict__ flag,
                            void* __restrict__ out) {
    const int b = blockIdx.x;
    const int n = threadIdx.x;
    const int bf = *flag;
    __shared__ float as_[32];
    if (n < 32) as_[n] = ldraw(a_raw, (size_t)b * kA + n, bf);
    __syncthreads();

    const _Float16* zp = z + (size_t)b * (kN * kA) + n * kA;
    float zl[32];
#pragma unroll
    for (int t = 0; t < 4; ++t) {
        half8 h = *(const half8*)(zp + t * 8);
#pragma unroll
        for (int j = 0; j < 8; ++j) zl[t * 8 + j] = (float)h[j];
    }
    float sum = 0.f;
#pragma unroll
    for (int a = 0; a < 32; ++a) {
        const float c = fast_tanh(zl[a]);  // MAX_A=1; bexp already in z
        const float d = c - as_[a];
        sum = fmaf(d, d, sum);
    }
    const float dist = sqrtf(sum + 0.01f);
    const float v = values[(size_t)b * kN + n];

    const int wid = n >> 6, lane = n & 63;
    __shared__ float red[8];
    __shared__ float rw[4], rwv[4];
    float m = dist;
    for (int off = 32; off > 0; off >>= 1) m = fminf(m, __shfl_down(m, off));
    if (lane == 0) red[wid] = m;
    __syncthreads();
    if (n == 0) red[4] = fminf(fminf(red[0], red[1]), fminf(red[2], red[3]));
    __syncthreads();
    const float dmin = red[4];

    float wgt = expf(dmin - dist);
    float wv = wgt * v;
    for (int off = 32; off > 0; off >>= 1) {
        wgt += __shfl_down(wgt, off);
        wv += __shfl_down(wv, off);
    }
    if (lane == 0) { rw[wid] = wgt; rwv[wid] = wv; }
    __syncthreads();
    if (n == 0) {
        const float sw = rw[0] + rw[1] + rw[2] + rw[3];
        const float swv = rwv[0] + rwv[1] + rwv[2] + rwv[3];
        const float o = swv / sw;
        if (bf) ((__hip_bfloat16*)out)[b] = __float2bfloat16(o);
        else    ((float*)out)[b] = o;
    }
}

extern "C" void kernel_launch(void* const* d_in, const int* in_sizes, int n_in,
                              void* d_out, int out_size, void* d_ws, size_t ws_size,
                              hipStream_t stream) {
    (void)in_sizes; (void)n_in; (void)out_size; (void)ws_size;
    char* ws = (char*)d_ws;
    int* flag = (int*)(ws + OFF_FLAG);
    _Float16* s16   = (_Float16*)(ws + OFF_S16);
    _Float16* wv1t  = (_Float16*)(ws + OFF_WV1T);
    _Float16* wv2t  = (_Float16*)(ws + OFF_WV2T);
    _Float16* wv3t  = (_Float16*)(ws + OFF_WV3T);
    _Float16* wv4t  = (_Float16*)(ws + OFF_WV4T);
    _Float16* wl1t  = (_Float16*)(ws + OFF_WL1T);
    _Float16* wexpt = (_Float16*)(ws + OFF_WEXPT);
    _Float16* buf1  = (_Float16*)(ws + OFF_BUF1);
    _Float16* buf2  = (_Float16*)(ws + OFF_BUF2);
    float* values   = (float*)(ws + OFF_VAL);
    _Float16* z     = (_Float16*)(ws + OFF_Z);

    detect_kernel<<<1, 256, 0, stream>>>((const unsigned int*)d_in[0], flag);
    convert_to_f16<<<512, 256, 0, stream>>>(d_in[0], s16, kB * kS, flag);

    TPack tp;
    tp.d[0] = {d_in[2],  wv1t,  kS, kH, (kH / 32) * (kS / 32)};          // 128
    tp.d[1] = {d_in[4],  wv2t,  kH, kH, (kH / 32) * (kH / 32)};          // 1024
    tp.d[2] = {d_in[6],  wv3t,  kH, kH, (kH / 32) * (kH / 32)};          // 1024
    tp.d[3] = {d_in[8],  wv4t,  kH, kN, (kN / 32) * (kH / 32)};          // 256
    tp.d[4] = {d_in[10], wl1t,  kS, kH, (kH / 32) * (kS / 32)};          // 128
    tp.d[5] = {d_in[12], wexpt, kH, kA, kN * (kA / 32) * (kH / 32)};     // 8192
    int total_tiles = 0;
    for (int i = 0; i < 6; ++i) total_tiles += tp.d[i].tiles;            // 10752
    transpose_all<<<total_tiles, dim3(8, 32), 0, stream>>>(tp, flag);

    // value MLP (1D grids, swizzled inside)
    dgemm<64, 64, 2, 2, 1, 1><<<(kB / 64) * (kH / 64), 256, 0, stream>>>(s16,  wv1t, d_in[3], buf1, flag, kH, kS, kB / 64, kH / 64);
    dgemm<128, 128, 2, 2, 1, 1><<<(kB / 128) * (kH / 128), 256, 0, stream>>>(buf1, wv2t, d_in[5], buf2, flag, kH, kH, kB / 128, kH / 128);
    dgemm<128, 128, 2, 2, 1, 1><<<(kB / 128) * (kH / 128), 256, 0, stream>>>(buf2, wv3t, d_in[7], buf1, flag, kH, kH, kB / 128, kH / 128);
    dgemm<64, 64, 2, 2, 0, 0><<<(kB / 64) * (kN / 64), 256, 0, stream>>>(buf1, wv4t, d_in[9], values, flag, kN, kH, kB / 64, kN / 64);
    // location hidden
    dgemm<64, 64, 2, 2, 1, 1><<<(kB / 64) * (kH / 64), 256, 0, stream>>>(s16,  wl1t, d_in[11], buf2, flag, kH, kS, kB / 64, kH / 64);
    // expert heads: z[B, N*A] = buf2 @ wexpt^T + bexp; 256x256 tile, 1024 thr (16 waves 4x4)
    dgemm<256, 256, 4, 4, 0, 1><<<(kB / 256) * ((kN * kA) / 256), 1024, 0, stream>>>(buf2, wexpt, d_in[13], z, flag, kN * kA, kH, kB / 256, (kN * kA) / 256);
    // fused tanh + distance + softmax + value readout
    final_fused<<<kB, 256, 0, stream>>>(z, d_in[1], values, flag, d_out);
}